// Round 4
// baseline (58.934 us; speedup 1.0000x reference)
//
#include <hip/hip_runtime.h>
#include <hip/hip_bf16.h>
#include <hip/hip_fp16.h>
#include <stdint.h>

// GGUF Q6_K fused dequant + GEMM:  out[16,14336] = x[16,4096] . W^T + bias
// Harness materializes uint8 w_q as int32 (one byte per dword, 192.7 MB).
// R4: no split-K, no atomics. Block = 4 waves = 16 output rows, full K=4096;
// wave wv handles super-blocks 4wv..4wv+3 (contiguous 3360B per row). Per-lane
// direct uint2 loads (dword-expanded bytes), SWAR dequant -> bf16 ->
// mfma_f32_16x16x32_bf16 (M=16 batch, N=16 rows, K=32). 4-wave LDS reduce,
// bias added in epilogue, single coalesced store. Grid 896.

#define OUT_F 14336
#define IN_F  4096
#define NB    16

using f32x4  = __attribute__((ext_vector_type(4))) float;
using short8 = __attribute__((ext_vector_type(8))) short;

__device__ __forceinline__ uint32_t pack_bf16(float lo, float hi) {
  return (__builtin_bit_cast(uint32_t, lo) >> 16) |
         (__builtin_bit_cast(uint32_t, hi) & 0xffff0000u);
}

__global__ __launch_bounds__(256)
void prep_kernel(const float* __restrict__ x, ushort* __restrict__ xbf)
{
  const int t = blockIdx.x * 256 + threadIdx.x;
  if (t < NB * IN_F) {
    uint32_t u = __builtin_bit_cast(uint32_t, x[t]);
    xbf[t] = (ushort)((u + 0x8000u) >> 16); // f32 -> bf16 round-to-nearest-ish
  }
}

template<bool USE_WS>
__global__ __launch_bounds__(256, 3)
void q6k_gemm(const int* __restrict__ wq,          // int32: one byte-value per dword
              const float* __restrict__ xf,
              const ushort* __restrict__ xbf,
              const float* __restrict__ bias,
              float* __restrict__ out)
{
  const int tid  = threadIdx.x;
  const int lane = tid & 63;
  const int wv   = tid >> 6;        // wave 0..3 -> k-slice of 1024
  const int l15  = lane & 15;       // output row within tile / x batch-col
  const int lg   = lane >> 4;       // k-octet group 0..3
  const int hb   = lg >> 1;         // scale byte half-select

  const int row = blockIdx.x * 16 + l15;
  const int* wbase = wq + (size_t)row * 3360 + wv * 840;   // wave's 4 super-blocks
  f32x4 acc = {0.f, 0.f, 0.f, 0.f};

  #pragma unroll 1
  for (int s = 0; s < 4; ++s) {
    const int* sbase = wbase + s * 210;
    const uint2 dd = *(const uint2*)(sbase + 208);
    const float dsup = __half2float(
        __builtin_bit_cast(__half, (uint16_t)((dd.x & 0xffu) | ((dd.y & 0xffu) << 8))));
    const int k_sb = wv * 1024 + s * 256 + 8 * lg;

    #pragma unroll
    for (int m = 0; m < 8; ++m) {
      // 8-element run e0 = 32m + 8lg
      const int* qlp = sbase + (m >> 2) * 64 + (m & 1) * 32 + 8 * lg;
      const int* qhp = sbase + 128 + (m >> 2) * 32 + 8 * lg;
      const uint2 a0 = *(const uint2*)(qlp);
      const uint2 a1 = *(const uint2*)(qlp + 2);
      const uint2 a2 = *(const uint2*)(qlp + 4);
      const uint2 a3 = *(const uint2*)(qlp + 6);
      const uint2 b0 = *(const uint2*)(qhp);
      const uint2 b1 = *(const uint2*)(qhp + 2);
      const uint2 b2 = *(const uint2*)(qhp + 4);
      const uint2 b3 = *(const uint2*)(qhp + 6);
      const uint2 scp = *(const uint2*)(sbase + 192 + 2 * m);   // scales 2m, 2m+1

      const int sc = (int)(int8_t)(uint8_t)(hb ? scp.y : scp.x);
      const float dl  = dsup * (float)sc;
      const float mdl = -32.0f * dl;

      const int SL = 4 * ((m >> 1) & 1);
      const int SH = 2 * (m & 3);
      auto dq = [&](uint32_t q, uint32_t h) -> float {
        const uint32_t t = ((q >> SL) & 15u) | (((h >> SH) & 3u) << 4);
        return fmaf((float)t, dl, mdl);
      };

      union { short8 s; uint32_t u[4]; } bfr;
      bfr.u[0] = pack_bf16(dq(a0.x, b0.x), dq(a0.y, b0.y));
      bfr.u[1] = pack_bf16(dq(a1.x, b1.x), dq(a1.y, b1.y));
      bfr.u[2] = pack_bf16(dq(a2.x, b2.x), dq(a2.y, b2.y));
      bfr.u[3] = pack_bf16(dq(a3.x, b3.x), dq(a3.y, b3.y));

      short8 afrag;
      if constexpr (USE_WS) {
        afrag = *(const short8*)(xbf + (size_t)l15 * IN_F + k_sb + m * 32);
      } else {
        const float* xp = xf + (size_t)l15 * IN_F + k_sb + m * 32;
        const f32x4 v0 = *(const f32x4*)(xp);
        const f32x4 v1 = *(const f32x4*)(xp + 4);
        union { short8 s; uint32_t u[4]; } av;
        av.u[0] = pack_bf16(v0[0], v0[1]);
        av.u[1] = pack_bf16(v0[2], v0[3]);
        av.u[2] = pack_bf16(v1[0], v1[1]);
        av.u[3] = pack_bf16(v1[2], v1[3]);
        afrag = av.s;
      }

      acc = __builtin_amdgcn_mfma_f32_16x16x32_bf16(afrag, bfr.s, acc, 0, 0, 0);
    }
  }

  // ---- cross-wave K reduction in LDS, then bias + single store ----
  // acc layout (m89-verified): col = lane&15 = output row, batch = lg*4 + reg
  __shared__ float red[4][64][4];
  *(f32x4*)(&red[wv][lane][0]) = acc;
  __syncthreads();

  const int b  = tid >> 4;          // batch 0..15
  const int r0 = tid & 15;          // row-in-tile 0..15
  const int ls = (b >> 2) * 16 + r0;
  const int rg = b & 3;
  const float sum = red[0][ls][rg] + red[1][ls][rg] + red[2][ls][rg] + red[3][ls][rg];
  const int orow = blockIdx.x * 16 + r0;
  out[(size_t)b * OUT_F + orow] = sum + bias[orow];
}

extern "C" void kernel_launch(void* const* d_in, const int* in_sizes, int n_in,
                              void* d_out, int out_size, void* d_ws, size_t ws_size,
                              hipStream_t stream)
{
  const float* x    = (const float*)d_in[0];
  const int*   wq   = (const int*)d_in[1];     // uint8 values materialized as int32
  const float* bias = (const float*)d_in[2];
  float*  out = (float*)d_out;
  ushort* xbf = (ushort*)d_ws;
  const bool use_ws = ws_size >= (size_t)NB * IN_F * 2;

  if (use_ws) {
    prep_kernel<<<dim3((NB * IN_F + 255) / 256), dim3(256), 0, stream>>>(x, xbf);
    q6k_gemm<true><<<dim3(OUT_F / 16), dim3(256), 0, stream>>>(wq, x, xbf, bias, out);
  } else {
    q6k_gemm<false><<<dim3(OUT_F / 16), dim3(256), 0, stream>>>(wq, x, xbf, bias, out);
  }
}

// Round 5
// 46.524 us; speedup vs baseline: 1.2668x; 1.2668x over previous
//
#include <hip/hip_runtime.h>
#include <hip/hip_bf16.h>
#include <hip/hip_fp16.h>
#include <stdint.h>

// GGUF Q6_K fused dequant + GEMM:  out[16,14336] = x[16,4096] . W^T + bias
// Harness materializes uint8 w_q as int32 (one byte-value per dword, 192.7MB).
// R5: coalesced streaming. Per block (16 rows, half of K): 4 phases, each
// staging a 16-row x 2-super-block panel (420 dw/row) into LDS via
// global_load_lds width=16 (64-lane + 41-lane calls, exact tile, no overread),
// double-buffered. Consumers read uint2 from LDS (row stride 420 dw = 2-way
// banks), per-element dequant -> bf16 -> mfma_f32_16x16x32_bf16.
// K-split 2 via f32 atomicAdd onto bias-prefilled out.

#define OUT_F 14336
#define IN_F  4096
#define NB    16

using f32x4  = __attribute__((ext_vector_type(4))) float;
using short8 = __attribute__((ext_vector_type(8))) short;

typedef const __attribute__((address_space(1))) void* gas1_t;
typedef __attribute__((address_space(3))) void* las3_t;

__device__ __forceinline__ void gload16(const uint32_t* g, uint32_t* l) {
  __builtin_amdgcn_global_load_lds((gas1_t)g, (las3_t)l, 16, 0, 0);
}

__device__ __forceinline__ uint32_t pack_bf16(float lo, float hi) {
  return (__builtin_bit_cast(uint32_t, lo) >> 16) |
         (__builtin_bit_cast(uint32_t, hi) & 0xffff0000u);
}

__global__ __launch_bounds__(256)
void prep_kernel(const float* __restrict__ x, const float* __restrict__ bias,
                 float* __restrict__ out, ushort* __restrict__ xbf, int use_ws)
{
  const int t = blockIdx.x * 256 + threadIdx.x;
  if (t < NB * OUT_F) {
    out[t] = bias[t % OUT_F];              // init out with bias; GEMM atomically adds
  }
  if (use_ws && t < NB * IN_F) {
    uint32_t u = __builtin_bit_cast(uint32_t, x[t]);
    xbf[t] = (ushort)((u + 0x8000u) >> 16); // f32 -> bf16
  }
}

constexpr int ROW_DW = 420;                // 2 super-blocks per row per phase
constexpr int ROW_B  = ROW_DW * 4;         // 1680 B; stride mod 32 banks = 4 -> 2-way
constexpr int BUF_B  = 16 * ROW_B;         // 26880 B per buffer

template<bool USE_WS>
__global__ __launch_bounds__(256, 3)
void q6k_gemm(const uint32_t* __restrict__ wq,     // int32: one byte-value per dword
              const float* __restrict__ xf,
              const ushort* __restrict__ xbf,
              float* __restrict__ out)
{
  __shared__ __align__(16) uint8_t wlds[2][BUF_B];

  const int tid  = threadIdx.x;
  const int lane = tid & 63;
  const int wv   = tid >> 6;        // wave 0..3
  const int l15  = lane & 15;       // row within tile / x batch
  const int lg   = lane >> 4;       // k-octet group 0..3
  const int bx   = blockIdx.x;      // row tile 0..895
  const int by   = blockIdx.y;      // k half 0..1
  const int row_base = bx * 16;
  const int sb_base  = by * 8;      // first super-block index of this half

  f32x4 acc = {0.f, 0.f, 0.f, 0.f};

  // ---- stage one phase: 16 rows x 420 dwords (sb pair 2p,2p+1) ----
  auto stage = [&](int buf, int ph) {
    const size_t gb = (size_t)row_base * 3360 + (size_t)(sb_base + 2 * ph) * 210;
    #pragma unroll
    for (int i = 0; i < 4; ++i) {
      const int r = wv * 4 + i;
      const uint32_t* g = wq + gb + (size_t)r * 3360;
      uint32_t* l = (uint32_t*)(&wlds[buf][r * ROW_B]);
      gload16(g + lane * 4, l);                              // dwords [0,256)
      if (lane < 41) gload16(g + 256 + lane * 4, l + 256);   // dwords [256,420)
    }
  };

  // ---- compute one phase from LDS ----
  auto compute = [&](int buf, int ph) {
    #pragma unroll
    for (int sb = 0; sb < 2; ++sb) {
      const uint8_t* rb = &wlds[buf][l15 * ROW_B + sb * 840];
      const uint2 dd = *(const uint2*)(rb + 832);
      const float dsup = __half2float(__builtin_bit_cast(__half,
                         (uint16_t)((dd.x & 0xffu) | ((dd.y & 0xffu) << 8))));
      #pragma unroll
      for (int mm = 0; mm < 2; ++mm) {
        const int m = 2 * wv + mm;                 // wave-uniform
        const uint8_t* qlp = rb + (m >> 2) * 256 + (m & 1) * 128 + lg * 32;
        const uint8_t* qhp = rb + 512 + (m >> 2) * 128 + lg * 32;
        const uint2 a0 = *(const uint2*)(qlp);
        const uint2 a1 = *(const uint2*)(qlp + 8);
        const uint2 a2 = *(const uint2*)(qlp + 16);
        const uint2 a3 = *(const uint2*)(qlp + 24);
        const uint2 b0 = *(const uint2*)(qhp);
        const uint2 b1 = *(const uint2*)(qhp + 8);
        const uint2 b2 = *(const uint2*)(qhp + 16);
        const uint2 b3 = *(const uint2*)(qhp + 24);
        const uint32_t scd = *(const uint32_t*)(rb + 768 + 8 * m + 4 * (lg >> 1));

        const float dl  = dsup * (float)(int)(int8_t)(uint8_t)scd;
        const float mdl = -32.0f * dl;
        const int SL = 4 * ((m >> 1) & 1);         // wave-uniform
        const int SH = 2 * (m & 3);
        auto dq = [&](uint32_t q, uint32_t h) -> float {
          const uint32_t t = ((q >> SL) & 15u) | (((h >> SH) & 3u) << 4);
          return fmaf((float)t, dl, mdl);
        };

        union { short8 s; uint32_t u[4]; } bfr;
        bfr.u[0] = pack_bf16(dq(a0.x, b0.x), dq(a0.y, b0.y));
        bfr.u[1] = pack_bf16(dq(a1.x, b1.x), dq(a1.y, b1.y));
        bfr.u[2] = pack_bf16(dq(a2.x, b2.x), dq(a2.y, b2.y));
        bfr.u[3] = pack_bf16(dq(a3.x, b3.x), dq(a3.y, b3.y));

        const int k0 = by * 2048 + (2 * ph + sb) * 256 + m * 32 + lg * 8;
        short8 afrag;
        if constexpr (USE_WS) {
          afrag = *(const short8*)(xbf + (size_t)l15 * IN_F + k0);
        } else {
          const float* xp = xf + (size_t)l15 * IN_F + k0;
          const f32x4 v0 = *(const f32x4*)(xp);
          const f32x4 v1 = *(const f32x4*)(xp + 4);
          union { short8 s; uint32_t u[4]; } av;
          av.u[0] = pack_bf16(v0[0], v0[1]);
          av.u[1] = pack_bf16(v0[2], v0[3]);
          av.u[2] = pack_bf16(v1[0], v1[1]);
          av.u[3] = pack_bf16(v1[2], v1[3]);
          afrag = av.s;
        }

        acc = __builtin_amdgcn_mfma_f32_16x16x32_bf16(afrag, bfr.s, acc, 0, 0, 0);
      }
    }
  };

  // ---- pipelined phases: stage(p+1) || compute(p), one barrier per phase ----
  stage(0, 0);
  __syncthreads();                       // drains vmcnt -> buf0 ready
  #pragma unroll
  for (int p = 0; p < 4; ++p) {
    if (p < 3) stage((p + 1) & 1, p + 1);
    compute(p & 1, p);
    __syncthreads();                     // readers done + next staging drained
  }

  // ---- cross-wave K reduction (alias LDS), then atomic add ----
  float (*red)[64][4] = (float (*)[64][4])(&wlds[0][0]);
  *(f32x4*)(&red[wv][lane][0]) = acc;
  __syncthreads();

  const int b  = tid >> 4;               // batch 0..15
  const int r0 = tid & 15;               // row-in-tile
  const int ls = (b >> 2) * 16 + r0;
  const int rg = b & 3;
  const float sum = red[0][ls][rg] + red[1][ls][rg] + red[2][ls][rg] + red[3][ls][rg];
  atomicAdd(&out[(size_t)b * OUT_F + row_base + r0], sum);
}

extern "C" void kernel_launch(void* const* d_in, const int* in_sizes, int n_in,
                              void* d_out, int out_size, void* d_ws, size_t ws_size,
                              hipStream_t stream)
{
  const float*    x    = (const float*)d_in[0];
  const uint32_t* wq   = (const uint32_t*)d_in[1];   // uint8 values as int32 dwords
  const float*    bias = (const float*)d_in[2];
  float*  out = (float*)d_out;
  ushort* xbf = (ushort*)d_ws;
  const bool use_ws = ws_size >= (size_t)NB * IN_F * 2;

  prep_kernel<<<dim3(896), dim3(256), 0, stream>>>(x, bias, out, xbf, use_ws ? 1 : 0);

  dim3 grid(OUT_F / 16, 2);
  if (use_ws) {
    q6k_gemm<true><<<grid, dim3(256), 0, stream>>>(wq, x, xbf, out);
  } else {
    q6k_gemm<false><<<grid, dim3(256), 0, stream>>>(wq, x, xbf, out);
  }
}

// Round 6
// 43.414 us; speedup vs baseline: 1.3575x; 1.0716x over previous
//
#include <hip/hip_runtime.h>
#include <hip/hip_bf16.h>
#include <hip/hip_fp16.h>
#include <stdint.h>

// GGUF Q6_K fused dequant + GEMM:  out[16,14336] = x[16,4096] . W^T + bias
// Harness materializes uint8 w_q as int32 (one byte-value per dword, 192.7MB).
// R6: 1-super-block phases, double-buffered (27.1KB LDS -> 5+ blocks/CU so
// cross-block TLP covers barrier drains). LDS row slot = 212 dwords (848B):
// b128 consumer reads start at banks = multiples of 4, uniform -> conflict-free
// minimum. Staging via global_load_lds w16 (lanes<52) + w4 (lanes<2), exact.
// Dequant SWAR -> bf16 -> mfma_f32_16x16x32_bf16; K-split 2 via atomicAdd.

#define OUT_F 14336
#define IN_F  4096
#define NB    16

using f32x4  = __attribute__((ext_vector_type(4))) float;
using short8 = __attribute__((ext_vector_type(8))) short;

typedef const __attribute__((address_space(1))) void* gas1_t;
typedef __attribute__((address_space(3))) void* las3_t;

__device__ __forceinline__ void gload16(const uint32_t* g, uint32_t* l) {
  __builtin_amdgcn_global_load_lds((gas1_t)g, (las3_t)l, 16, 0, 0);
}
__device__ __forceinline__ void gload4(const uint32_t* g, uint32_t* l) {
  __builtin_amdgcn_global_load_lds((gas1_t)g, (las3_t)l, 4, 0, 0);
}

__device__ __forceinline__ uint32_t pack_bf16(float lo, float hi) {
  return (__builtin_bit_cast(uint32_t, lo) >> 16) |
         (__builtin_bit_cast(uint32_t, hi) & 0xffff0000u);
}

__global__ __launch_bounds__(256)
void prep_kernel(const float* __restrict__ x, const float* __restrict__ bias,
                 float* __restrict__ out, ushort* __restrict__ xbf, int use_ws)
{
  const int t = blockIdx.x * 256 + threadIdx.x;
  if (t < NB * OUT_F) {
    out[t] = bias[t % OUT_F];              // init out with bias; GEMM atomically adds
  }
  if (use_ws && t < NB * IN_F) {
    uint32_t u = __builtin_bit_cast(uint32_t, x[t]);
    xbf[t] = (ushort)((u + 0x8000u) >> 16); // f32 -> bf16
  }
}

constexpr int ROW_DW = 212;                // 210 data dwords + 2 pad (bank spread)
constexpr int ROW_B  = ROW_DW * 4;         // 848 B, 16B-aligned rows
constexpr int BUF_B  = 16 * ROW_B;         // 13568 B per buffer

template<bool USE_WS>
__global__ __launch_bounds__(256, 5)
void q6k_gemm(const uint32_t* __restrict__ wq,     // int32: one byte-value per dword
              const float* __restrict__ xf,
              const ushort* __restrict__ xbf,
              float* __restrict__ out)
{
  __shared__ __align__(16) uint8_t wlds[2][BUF_B];

  const int tid  = threadIdx.x;
  const int lane = tid & 63;
  const int wv   = tid >> 6;        // wave 0..3
  const int l15  = lane & 15;       // row within tile / x batch
  const int lg   = lane >> 4;       // k-octet group 0..3
  const int bx   = blockIdx.x;      // row tile 0..895
  const int by   = blockIdx.y;      // k half 0..1
  const int row_base = bx * 16;
  const int sb0 = by * 8;           // first super-block of this k half

  f32x4 acc = {0.f, 0.f, 0.f, 0.f};

  // ---- stage one super-block panel: 16 rows x 210 dwords ----
  auto stage = [&](int buf, int ph) {
    const size_t gb = (size_t)row_base * 3360 + (size_t)(sb0 + ph) * 210;
    #pragma unroll
    for (int i = 0; i < 4; ++i) {
      const int r = wv * 4 + i;
      const uint32_t* g = wq + gb + (size_t)r * 3360;
      uint32_t* l = (uint32_t*)(&wlds[buf][r * ROW_B]);
      if (lane < 52) gload16(g + lane * 4, l);          // dwords [0,208)
      if (lane < 2)  gload4(g + 208 + lane, l + 208);   // dwords 208,209
    }
  };

  // ---- compute one super-block from LDS ----
  auto compute = [&](int buf, int ph) {
    const uint8_t* rb = &wlds[buf][l15 * ROW_B];
    const uint2 dd = *(const uint2*)(rb + 832);
    const float dsup = __half2float(__builtin_bit_cast(__half,
                       (uint16_t)((dd.x & 0xffu) | ((dd.y & 0xffu) << 8))));
    #pragma unroll
    for (int mm = 0; mm < 2; ++mm) {
      const int m = 2 * wv + mm;                 // wave-uniform
      const uint8_t* qlp = rb + (m >> 2) * 256 + (m & 1) * 128 + lg * 32;
      const uint8_t* qhp = rb + 512 + (m >> 2) * 128 + lg * 32;
      const uint4 A0 = *(const uint4*)(qlp);
      const uint4 A1 = *(const uint4*)(qlp + 16);
      const uint4 B0 = *(const uint4*)(qhp);
      const uint4 B1 = *(const uint4*)(qhp + 16);
      const uint32_t scd = *(const uint32_t*)(rb + 768 + 8 * m + 4 * (lg >> 1));

      const float dl  = dsup * (float)(int)(int8_t)(uint8_t)scd;
      const float mdl = -32.0f * dl;
      const int SL = 4 * ((m >> 1) & 1);         // wave-uniform
      const int SH = 2 * (m & 3);
      auto dq = [&](uint32_t q, uint32_t h) -> float {
        const uint32_t t = ((q >> SL) & 15u) | (((h >> SH) & 3u) << 4);
        return fmaf((float)t, dl, mdl);
      };

      union { short8 s; uint32_t u[4]; } bfr;
      bfr.u[0] = pack_bf16(dq(A0.x, B0.x), dq(A0.y, B0.y));
      bfr.u[1] = pack_bf16(dq(A0.z, B0.z), dq(A0.w, B0.w));
      bfr.u[2] = pack_bf16(dq(A1.x, B1.x), dq(A1.y, B1.y));
      bfr.u[3] = pack_bf16(dq(A1.z, B1.z), dq(A1.w, B1.w));

      const int k0 = by * 2048 + ph * 256 + m * 32 + lg * 8;
      short8 afrag;
      if constexpr (USE_WS) {
        afrag = *(const short8*)(xbf + (size_t)l15 * IN_F + k0);
      } else {
        const float* xp = xf + (size_t)l15 * IN_F + k0;
        const f32x4 v0 = *(const f32x4*)(xp);
        const f32x4 v1 = *(const f32x4*)(xp + 4);
        union { short8 s; uint32_t u[4]; } av;
        av.u[0] = pack_bf16(v0[0], v0[1]);
        av.u[1] = pack_bf16(v0[2], v0[3]);
        av.u[2] = pack_bf16(v1[0], v1[1]);
        av.u[3] = pack_bf16(v1[2], v1[3]);
        afrag = av.s;
      }

      acc = __builtin_amdgcn_mfma_f32_16x16x32_bf16(afrag, bfr.s, acc, 0, 0, 0);
    }
  };

  // ---- pipelined phases: stage(p+1) || compute(p), one barrier per phase ----
  stage(0, 0);
  __syncthreads();
  #pragma unroll
  for (int p = 0; p < 8; ++p) {
    if (p < 7) stage((p + 1) & 1, p + 1);
    compute(p & 1, p);
    __syncthreads();
  }

  // ---- cross-wave K reduction (alias LDS), then atomic add ----
  float (*red)[64][4] = (float (*)[64][4])(&wlds[0][0]);
  *(f32x4*)(&red[wv][lane][0]) = acc;
  __syncthreads();

  const int b  = tid >> 4;               // batch 0..15
  const int r0 = tid & 15;               // row-in-tile
  const int ls = (b >> 2) * 16 + r0;
  const int rg = b & 3;
  const float sum = red[0][ls][rg] + red[1][ls][rg] + red[2][ls][rg] + red[3][ls][rg];
  atomicAdd(&out[(size_t)b * OUT_F + row_base + r0], sum);
}

extern "C" void kernel_launch(void* const* d_in, const int* in_sizes, int n_in,
                              void* d_out, int out_size, void* d_ws, size_t ws_size,
                              hipStream_t stream)
{
  const float*    x    = (const float*)d_in[0];
  const uint32_t* wq   = (const uint32_t*)d_in[1];   // uint8 values as int32 dwords
  const float*    bias = (const float*)d_in[2];
  float*  out = (float*)d_out;
  ushort* xbf = (ushort*)d_ws;
  const bool use_ws = ws_size >= (size_t)NB * IN_F * 2;

  prep_kernel<<<dim3(896), dim3(256), 0, stream>>>(x, bias, out, xbf, use_ws ? 1 : 0);

  dim3 grid(OUT_F / 16, 2);
  if (use_ws) {
    q6k_gemm<true><<<grid, dim3(256), 0, stream>>>(wq, x, xbf, out);
  } else {
    q6k_gemm<false><<<grid, dim3(256), 0, stream>>>(wq, x, xbf, out);
  }
}